// Round 7
// baseline (515.438 us; speedup 1.0000x reference)
//
#include <hip/hip_runtime.h>
#include <hip/hip_bf16.h>

#define H 2048
#define RIN 2304
#define SW 256
#define SD 200
#define NBLK 1024
#define NWAVE 4096   // 1024 blocks * 4 waves

// ws layout (floats):
#define WS_CDOT 0
#define WS_SDOT 4
#define WS_GH0  260
#define WS_GH1  6404
#define WS_GI0  12548
#define WS_BAR  18692   // 3 ints, zeroed by hipMemsetAsync each call

// out layout (floats): [0..100) logits, [100..2148) h0, [2148..4196) h1,
// [4196..55396) new_stack (200x256)

typedef __attribute__((ext_vector_type(4))) float f32x4;

__device__ __forceinline__ float wave_reduce(float acc) {
  #pragma unroll
  for (int off = 32; off > 0; off >>= 1) acc += __shfl_down(acc, off);
  return acc;  // valid in lane 0
}

__device__ __forceinline__ float sigmoidf(float x) {
  return 1.f / (1.f + expf(-x));
}

// R2-style one-shot 2048-dot partial (best measured k1 shape across R1-R6).
__device__ __forceinline__ float dot2048_part(const float* __restrict__ w,
                                              const float* __restrict__ x) {
  int lane = threadIdx.x & 63;
  const f32x4* w4 = (const f32x4*)w + lane;
  const f32x4* x4 = (const f32x4*)x + lane;
  f32x4 a0 = w4[0],   a1 = w4[64],  a2 = w4[128], a3 = w4[192];
  f32x4 a4 = w4[256], a5 = w4[320], a6 = w4[384], a7 = w4[448];
  f32x4 b0 = x4[0],   b1 = x4[64],  b2 = x4[128], b3 = x4[192];
  f32x4 b4 = x4[256], b5 = x4[320], b6 = x4[384], b7 = x4[448];
  f32x4 s = a0 * b0;
  s += a1 * b1; s += a2 * b2; s += a3 * b3;
  s += a4 * b4; s += a5 * b5; s += a6 * b6; s += a7 * b7;
  return s[0] + s[1] + s[2] + s[3];
}

// Device-scope grid barrier. Safe because all NBLK blocks are co-resident by
// construction (launch_bounds(256,4) => 4 blocks/CU * 256 CU = 1024 = NBLK).
// Counter zeroed per call by hipMemsetAsync. threadfence after release
// invalidates L1/L2 so reads can't see stale lines from a previous replay.
__device__ __forceinline__ void grid_barrier(int* bar, int phase) {
  __syncthreads();              // block's stores done (waitcnt before barrier)
  if (threadIdx.x == 0) {
    __threadfence();            // release: block's writes visible device-wide
    atomicAdd(bar + phase, 1);
    while (atomicAdd(bar + phase, 0) < NBLK) __builtin_amdgcn_s_sleep(7);
  }
  __syncthreads();
  __threadfence();              // acquire in every thread
}

__global__ __launch_bounds__(256, 4)
void fused(const float* __restrict__ hidden, const int* __restrict__ inp,
           const float* __restrict__ emb, const float* __restrict__ stack,
           const float* __restrict__ Wc, const float* __restrict__ bc,
           const float* __restrict__ Ws, const float* __restrict__ bs,
           const float* __restrict__ Wih0, const float* __restrict__ bih0,
           const float* __restrict__ Whh0, const float* __restrict__ bhh0,
           const float* __restrict__ Wih1, const float* __restrict__ bih1,
           const float* __restrict__ Whh1, const float* __restrict__ bhh1,
           const float* __restrict__ Wd, const float* __restrict__ bd,
           float* __restrict__ ws, float* __restrict__ out) {
  int t = threadIdx.x;
  int lane = t & 63;
  int wgid = blockIdx.x * 4 + (t >> 6);
  int* bar = (int*)(ws + WS_BAR);

  // ---------------- Phase 1: all input-only matvecs (155 MB) ----------------
  for (int u = wgid; u < 18691; u += NWAVE) {
    if (u < 6144) {
      float d = wave_reduce(dot2048_part(Whh0 + (size_t)u * H, hidden));
      if (lane == 0) ws[WS_GH0 + u] = d + bhh0[u];
    } else if (u < 12288) {
      int r = u - 6144;
      float d = wave_reduce(dot2048_part(Whh1 + (size_t)r * H, hidden + H));
      if (lane == 0) ws[WS_GH1 + r] = d + bhh1[r];
    } else if (u < 18432) {
      int r = u - 12288;
      const float* erow = emb + (size_t)inp[0] * H;
      float d = wave_reduce(dot2048_part(Wih0 + (size_t)r * RIN, erow));
      if (lane == 0) ws[WS_GI0 + r] = d + bih0[r];
    } else if (u < 18688) {
      int r = u - 18432;
      const float* wr = Ws + (size_t)r * (2 * H);
      float d = wave_reduce(dot2048_part(wr, hidden) +
                            dot2048_part(wr + H, hidden + H));
      if (lane == 0) ws[WS_SDOT + r] = d + bs[r];
    } else {
      int r = u - 18688;
      const float* wr = Wc + (size_t)r * (2 * H);
      float d = wave_reduce(dot2048_part(wr, hidden) +
                            dot2048_part(wr + H, hidden + H));
      if (lane == 0) ws[WS_CDOT + r] = d + bc[r];
    }
  }
  grid_barrier(bar, 0);

  // ------- Phase 2: stack update + GRU layer0 finish (wave-per-unit) --------
  {
    float c0 = ws[WS_CDOT + 0], c1 = ws[WS_CDOT + 1], c2 = ws[WS_CDOT + 2];
    float m = fmaxf(c0, fmaxf(c1, c2));
    float e0 = expf(c0 - m), e1 = expf(c1 - m), e2 = expf(c2 - m);
    float inv = 1.f / (e0 + e1 + e2);
    float a_push = e0 * inv, a_pop = e1 * inv, a_noop = e2 * inv;
    int lane4 = lane * 4;

    if (wgid < 2048) {
      int j = wgid;
      // stacktop per-lane (4 cols each): no LDS, no extra syncs
      f32x4 s0 = *(const f32x4*)(stack + lane4);
      f32x4 s1 = *(const f32x4*)(stack + SW + lane4);
      f32x4 sd = *(const f32x4*)(ws + WS_SDOT + lane4);
      f32x4 st;
      #pragma unroll
      for (int c = 0; c < 4; ++c)
        st[c] = a_noop * s0[c] + a_push * tanhf(sd[c]) + a_pop * s1[c];
      // three K=256 gate dots of Wih0 stack columns
      float g[3];
      #pragma unroll
      for (int gate = 0; gate < 3; ++gate) {
        const f32x4* wrow =
            (const f32x4*)(Wih0 + (size_t)(gate * H + j) * RIN + H);
        f32x4 p = wrow[lane] * st;
        g[gate] = wave_reduce(p[0] + p[1] + p[2] + p[3]);
      }
      if (lane == 0) {
        float r = sigmoidf(ws[WS_GI0 + j] + g[0] + ws[WS_GH0 + j]);
        float z = sigmoidf(ws[WS_GI0 + H + j] + g[1] + ws[WS_GH0 + H + j]);
        float n = tanhf(ws[WS_GI0 + 2 * H + j] + g[2] +
                        r * ws[WS_GH0 + 2 * H + j]);
        out[100 + j] = (1.f - z) * n + z * hidden[j];
      }
    } else if (wgid < 2048 + SD) {
      int r = wgid - 2048;
      f32x4 cur = *(const f32x4*)(stack + r * SW + lane4);
      f32x4 up, down;
      if (r == 0) {
        f32x4 sd = *(const f32x4*)(ws + WS_SDOT + lane4);
        #pragma unroll
        for (int c = 0; c < 4; ++c) up[c] = tanhf(sd[c]);
      } else {
        up = *(const f32x4*)(stack + (r - 1) * SW + lane4);
      }
      if (r == SD - 1) down = (f32x4)(0.f);
      else down = *(const f32x4*)(stack + (r + 1) * SW + lane4);
      f32x4 res = a_noop * cur + a_push * up + a_pop * down;
      *(f32x4*)(out + 4196 + r * SW + lane4) = res;
    }
  }
  grid_barrier(bar, 1);

  // ---------------- Phase 3: GRU layer1 (Wih1 @ h0, 50 MB) -----------------
  if (wgid < 2048) {
    int j = wgid;
    const float* h0 = out + 100;
    float pr = dot2048_part(Wih1 + (size_t)j * H, h0);
    float pz = dot2048_part(Wih1 + (size_t)(H + j) * H, h0);
    float pn = dot2048_part(Wih1 + (size_t)(2 * H + j) * H, h0);
    float dr = wave_reduce(pr);
    float dz = wave_reduce(pz);
    float dn = wave_reduce(pn);
    if (lane == 0) {
      float r = sigmoidf(dr + bih1[j] + ws[WS_GH1 + j]);
      float z = sigmoidf(dz + bih1[H + j] + ws[WS_GH1 + H + j]);
      float n = tanhf(dn + bih1[2 * H + j] + r * ws[WS_GH1 + 2 * H + j]);
      out[100 + H + j] = (1.f - z) * n + z * hidden[H + j];
    }
  }
  grid_barrier(bar, 2);

  // ---------------- Phase 4: logits = Wd @ h1 + bd (0.8 MB) ----------------
  if (wgid < 100) {
    const float* h1 = out + 100 + H;
    float d = wave_reduce(dot2048_part(Wd + (size_t)wgid * H, h1));
    if (lane == 0) out[wgid] = d + bd[wgid];
  }
}

extern "C" void kernel_launch(void* const* d_in, const int* in_sizes, int n_in,
                              void* d_out, int out_size, void* d_ws, size_t ws_size,
                              hipStream_t stream) {
  const int*   inp    = (const int*)d_in[0];
  const float* hidden = (const float*)d_in[1];
  const float* stack  = (const float*)d_in[2];
  const float* emb    = (const float*)d_in[3];
  const float* Wc     = (const float*)d_in[4];
  const float* bc     = (const float*)d_in[5];
  const float* Ws     = (const float*)d_in[6];
  const float* bs     = (const float*)d_in[7];
  const float* Wih0   = (const float*)d_in[8];
  const float* Whh0   = (const float*)d_in[9];
  const float* bih0   = (const float*)d_in[10];
  const float* bhh0   = (const float*)d_in[11];
  const float* Wih1   = (const float*)d_in[12];
  const float* Whh1   = (const float*)d_in[13];
  const float* bih1   = (const float*)d_in[14];
  const float* bhh1   = (const float*)d_in[15];
  const float* Wd     = (const float*)d_in[16];
  const float* bd     = (const float*)d_in[17];
  float* ws  = (float*)d_ws;
  float* out = (float*)d_out;

  // zero the 3 barrier counters (d_ws is poisoned 0xAA once, never re-poisoned)
  hipMemsetAsync((char*)d_ws + WS_BAR * sizeof(float), 0, 3 * sizeof(int), stream);
  fused<<<NBLK, 256, 0, stream>>>(hidden, inp, emb, stack, Wc, bc, Ws, bs,
                                  Wih0, bih0, Whh0, bhh0, Wih1, bih1,
                                  Whh1, bhh1, Wd, bd, ws, out);
}

// Round 8
// 505.610 us; speedup vs baseline: 1.0194x; 1.0194x over previous
//
#include <hip/hip_runtime.h>
#include <hip/hip_bf16.h>

#define H 2048
#define RIN 2304
#define SW 256
#define SD 200
#define NBLK 1024
#define NWAVE 4096   // 1024 blocks * 4 waves

// ws layout (floats):
#define WS_CDOT 0
#define WS_SDOT 4
#define WS_GH0  260
#define WS_GH1  6404
#define WS_GI0  12548
#define WS_BAR  18692   // 3 ints, zeroed by hipMemsetAsync each call

// out layout (floats): [0..100) logits, [100..2148) h0, [2148..4196) h1,
// [4196..55396) new_stack (200x256)

typedef __attribute__((ext_vector_type(4))) float f32x4;

__device__ __forceinline__ float wave_reduce(float acc) {
  #pragma unroll
  for (int off = 32; off > 0; off >>= 1) acc += __shfl_down(acc, off);
  return acc;  // valid in lane 0
}

__device__ __forceinline__ float sigmoidf(float x) {
  return 1.f / (1.f + expf(-x));
}

// R2-style one-shot 2048-dot partial (best measured k1 shape across R1-R6).
__device__ __forceinline__ float dot2048_part(const float* __restrict__ w,
                                              const float* __restrict__ x) {
  int lane = threadIdx.x & 63;
  const f32x4* w4 = (const f32x4*)w + lane;
  const f32x4* x4 = (const f32x4*)x + lane;
  f32x4 a0 = w4[0],   a1 = w4[64],  a2 = w4[128], a3 = w4[192];
  f32x4 a4 = w4[256], a5 = w4[320], a6 = w4[384], a7 = w4[448];
  f32x4 b0 = x4[0],   b1 = x4[64],  b2 = x4[128], b3 = x4[192];
  f32x4 b4 = x4[256], b5 = x4[320], b6 = x4[384], b7 = x4[448];
  f32x4 s = a0 * b0;
  s += a1 * b1; s += a2 * b2; s += a3 * b3;
  s += a4 * b4; s += a5 * b5; s += a6 * b6; s += a7 * b7;
  return s[0] + s[1] + s[2] + s[3];
}

// Device-scope grid barrier. All NBLK blocks co-resident by construction
// (launch_bounds(256,4) => 4 blocks/CU * 256 CU = 1024 = NBLK).
// R7 lesson: polling with atomicAdd(p,0) is an RMW -> 1024 pollers serialize
// at the coherence point (~200us/round, 10x regression). Poll with an
// agent-scope atomic LOAD instead (cache-bypassing global_load, read-only,
// served concurrently); arrival remains a single RMW per block.
__device__ __forceinline__ void grid_barrier(int* bar, int phase) {
  __syncthreads();              // block's stores done
  if (threadIdx.x == 0) {
    __threadfence();            // release: block's writes visible device-wide
    atomicAdd(bar + phase, 1);
    while (__hip_atomic_load(bar + phase, __ATOMIC_RELAXED,
                             __HIP_MEMORY_SCOPE_AGENT) < NBLK)
      __builtin_amdgcn_s_sleep(16);
  }
  __syncthreads();
  __threadfence();              // acquire in every thread
}

__global__ __launch_bounds__(256, 4)
void fused(const float* __restrict__ hidden, const int* __restrict__ inp,
           const float* __restrict__ emb, const float* __restrict__ stack,
           const float* __restrict__ Wc, const float* __restrict__ bc,
           const float* __restrict__ Ws, const float* __restrict__ bs,
           const float* __restrict__ Wih0, const float* __restrict__ bih0,
           const float* __restrict__ Whh0, const float* __restrict__ bhh0,
           const float* __restrict__ Wih1, const float* __restrict__ bih1,
           const float* __restrict__ Whh1, const float* __restrict__ bhh1,
           const float* __restrict__ Wd, const float* __restrict__ bd,
           float* __restrict__ ws, float* __restrict__ out) {
  int t = threadIdx.x;
  int lane = t & 63;
  int wgid = blockIdx.x * 4 + (t >> 6);
  int* bar = (int*)(ws + WS_BAR);

  // ---------------- Phase 1: all input-only matvecs (155 MB) ----------------
  for (int u = wgid; u < 18691; u += NWAVE) {
    if (u < 6144) {
      float d = wave_reduce(dot2048_part(Whh0 + (size_t)u * H, hidden));
      if (lane == 0) ws[WS_GH0 + u] = d + bhh0[u];
    } else if (u < 12288) {
      int r = u - 6144;
      float d = wave_reduce(dot2048_part(Whh1 + (size_t)r * H, hidden + H));
      if (lane == 0) ws[WS_GH1 + r] = d + bhh1[r];
    } else if (u < 18432) {
      int r = u - 12288;
      const float* erow = emb + (size_t)inp[0] * H;
      float d = wave_reduce(dot2048_part(Wih0 + (size_t)r * RIN, erow));
      if (lane == 0) ws[WS_GI0 + r] = d + bih0[r];
    } else if (u < 18688) {
      int r = u - 18432;
      const float* wr = Ws + (size_t)r * (2 * H);
      float d = wave_reduce(dot2048_part(wr, hidden) +
                            dot2048_part(wr + H, hidden + H));
      if (lane == 0) ws[WS_SDOT + r] = d + bs[r];
    } else {
      int r = u - 18688;
      const float* wr = Wc + (size_t)r * (2 * H);
      float d = wave_reduce(dot2048_part(wr, hidden) +
                            dot2048_part(wr + H, hidden + H));
      if (lane == 0) ws[WS_CDOT + r] = d + bc[r];
    }
  }
  grid_barrier(bar, 0);

  // ------- Phase 2: stack update + GRU layer0 finish (wave-per-unit) --------
  {
    float c0 = ws[WS_CDOT + 0], c1 = ws[WS_CDOT + 1], c2 = ws[WS_CDOT + 2];
    float m = fmaxf(c0, fmaxf(c1, c2));
    float e0 = expf(c0 - m), e1 = expf(c1 - m), e2 = expf(c2 - m);
    float inv = 1.f / (e0 + e1 + e2);
    float a_push = e0 * inv, a_pop = e1 * inv, a_noop = e2 * inv;
    int lane4 = lane * 4;

    if (wgid < 2048) {
      int j = wgid;
      // stacktop per-lane (4 cols each): no LDS, no extra syncs
      f32x4 s0 = *(const f32x4*)(stack + lane4);
      f32x4 s1 = *(const f32x4*)(stack + SW + lane4);
      f32x4 sd = *(const f32x4*)(ws + WS_SDOT + lane4);
      f32x4 st;
      #pragma unroll
      for (int c = 0; c < 4; ++c)
        st[c] = a_noop * s0[c] + a_push * tanhf(sd[c]) + a_pop * s1[c];
      // three K=256 gate dots of Wih0 stack columns
      float g[3];
      #pragma unroll
      for (int gate = 0; gate < 3; ++gate) {
        const f32x4* wrow =
            (const f32x4*)(Wih0 + (size_t)(gate * H + j) * RIN + H);
        f32x4 p = wrow[lane] * st;
        g[gate] = wave_reduce(p[0] + p[1] + p[2] + p[3]);
      }
      if (lane == 0) {
        float r = sigmoidf(ws[WS_GI0 + j] + g[0] + ws[WS_GH0 + j]);
        float z = sigmoidf(ws[WS_GI0 + H + j] + g[1] + ws[WS_GH0 + H + j]);
        float n = tanhf(ws[WS_GI0 + 2 * H + j] + g[2] +
                        r * ws[WS_GH0 + 2 * H + j]);
        out[100 + j] = (1.f - z) * n + z * hidden[j];
      }
    } else if (wgid < 2048 + SD) {
      int r = wgid - 2048;
      f32x4 cur = *(const f32x4*)(stack + r * SW + lane4);
      f32x4 up, down;
      if (r == 0) {
        f32x4 sd = *(const f32x4*)(ws + WS_SDOT + lane4);
        #pragma unroll
        for (int c = 0; c < 4; ++c) up[c] = tanhf(sd[c]);
      } else {
        up = *(const f32x4*)(stack + (r - 1) * SW + lane4);
      }
      if (r == SD - 1) down = (f32x4)(0.f);
      else down = *(const f32x4*)(stack + (r + 1) * SW + lane4);
      f32x4 res = a_noop * cur + a_push * up + a_pop * down;
      *(f32x4*)(out + 4196 + r * SW + lane4) = res;
    }
  }
  grid_barrier(bar, 1);

  // ---------------- Phase 3: GRU layer1 (Wih1 @ h0, 50 MB) -----------------
  if (wgid < 2048) {
    int j = wgid;
    const float* h0 = out + 100;
    float pr = dot2048_part(Wih1 + (size_t)j * H, h0);
    float pz = dot2048_part(Wih1 + (size_t)(H + j) * H, h0);
    float pn = dot2048_part(Wih1 + (size_t)(2 * H + j) * H, h0);
    float dr = wave_reduce(pr);
    float dz = wave_reduce(pz);
    float dn = wave_reduce(pn);
    if (lane == 0) {
      float r = sigmoidf(dr + bih1[j] + ws[WS_GH1 + j]);
      float z = sigmoidf(dz + bih1[H + j] + ws[WS_GH1 + H + j]);
      float n = tanhf(dn + bih1[2 * H + j] + r * ws[WS_GH1 + 2 * H + j]);
      out[100 + H + j] = (1.f - z) * n + z * hidden[H + j];
    }
  }
  grid_barrier(bar, 2);

  // ---------------- Phase 4: logits = Wd @ h1 + bd (0.8 MB) ----------------
  if (wgid < 100) {
    const float* h1 = out + 100 + H;
    float d = wave_reduce(dot2048_part(Wd + (size_t)wgid * H, h1));
    if (lane == 0) out[wgid] = d + bd[wgid];
  }
}

extern "C" void kernel_launch(void* const* d_in, const int* in_sizes, int n_in,
                              void* d_out, int out_size, void* d_ws, size_t ws_size,
                              hipStream_t stream) {
  const int*   inp    = (const int*)d_in[0];
  const float* hidden = (const float*)d_in[1];
  const float* stack  = (const float*)d_in[2];
  const float* emb    = (const float*)d_in[3];
  const float* Wc     = (const float*)d_in[4];
  const float* bc     = (const float*)d_in[5];
  const float* Ws     = (const float*)d_in[6];
  const float* bs     = (const float*)d_in[7];
  const float* Wih0   = (const float*)d_in[8];
  const float* Whh0   = (const float*)d_in[9];
  const float* bih0   = (const float*)d_in[10];
  const float* bhh0   = (const float*)d_in[11];
  const float* Wih1   = (const float*)d_in[12];
  const float* Whh1   = (const float*)d_in[13];
  const float* bih1   = (const float*)d_in[14];
  const float* bhh1   = (const float*)d_in[15];
  const float* Wd     = (const float*)d_in[16];
  const float* bd     = (const float*)d_in[17];
  float* ws  = (float*)d_ws;
  float* out = (float*)d_out;

  // zero the 3 barrier counters (d_ws is poisoned 0xAA once, never re-poisoned)
  hipMemsetAsync((char*)d_ws + WS_BAR * sizeof(float), 0, 3 * sizeof(int), stream);
  fused<<<NBLK, 256, 0, stream>>>(hidden, inp, emb, stack, Wc, bc, Ws, bs,
                                  Wih0, bih0, Whh0, bhh0, Wih1, bih1,
                                  Whh1, bhh1, Wd, bd, ws, out);
}

// Round 9
// 178.680 us; speedup vs baseline: 2.8847x; 2.8297x over previous
//
#include <hip/hip_runtime.h>
#include <hip/hip_bf16.h>

#define H 2048
#define RIN 2304
#define SW 256
#define SD 200
#define NBLK 1024
#define NWAVE 4096   // 1024 blocks * 4 waves

// ws layout (floats):
#define WS_CDOT 0
#define WS_SDOT 4
#define WS_GH0  260
#define WS_GH1  6404
#define WS_GI0  12548
#define WS_BAR  18692   // 3 ints, zeroed by hipMemsetAsync each call

// out layout (floats): [0..100) logits, [100..2148) h0, [2148..4196) h1,
// [4196..55396) new_stack (200x256)

typedef __attribute__((ext_vector_type(4))) float f32x4;

// Cross-XCD communication WITHOUT fences: agent-scope RELAXED atomics compile
// to plain sc1 loads/stores (coherent at Infinity Cache, bypass the stale
// per-XCD L2) and emit NO buffer_wbl2/buffer_inv. R7/R8 showed the
// __threadfence() pair per barrier costs ~170us each (fixed, data-independent:
// replays with 0.6MB HBM traffic still took 565us) -> fences are banned.
__device__ __forceinline__ float gload(const float* p) {
  return __hip_atomic_load(p, __ATOMIC_RELAXED, __HIP_MEMORY_SCOPE_AGENT);
}
__device__ __forceinline__ void gstore(float* p, float v) {
  __hip_atomic_store(p, v, __ATOMIC_RELAXED, __HIP_MEMORY_SCOPE_AGENT);
}

__device__ __forceinline__ float wave_reduce(float acc) {
  #pragma unroll
  for (int off = 32; off > 0; off >>= 1) acc += __shfl_down(acc, off);
  return acc;  // valid in lane 0
}

__device__ __forceinline__ float sigmoidf(float x) {
  return 1.f / (1.f + expf(-x));
}

// One-shot 2048-dot partial, x from global (read-only inputs, normal loads).
__device__ __forceinline__ float dot2048_part(const float* __restrict__ w,
                                              const float* __restrict__ x) {
  int lane = threadIdx.x & 63;
  const f32x4* w4 = (const f32x4*)w + lane;
  const f32x4* x4 = (const f32x4*)x + lane;
  f32x4 a0 = w4[0],   a1 = w4[64],  a2 = w4[128], a3 = w4[192];
  f32x4 a4 = w4[256], a5 = w4[320], a6 = w4[384], a7 = w4[448];
  f32x4 b0 = x4[0],   b1 = x4[64],  b2 = x4[128], b3 = x4[192];
  f32x4 b4 = x4[256], b5 = x4[320], b6 = x4[384], b7 = x4[448];
  f32x4 s = a0 * b0;
  s += a1 * b1; s += a2 * b2; s += a3 * b3;
  s += a4 * b4; s += a5 * b5; s += a6 * b6; s += a7 * b7;
  return s[0] + s[1] + s[2] + s[3];
}

// 2048-dot partial with x in LDS (phase 3/4: x is cross-phase data, staged
// once per block via sc1 loads).
__device__ __forceinline__ float row_dot_lds(const float* __restrict__ Wrow,
                                             const float* __restrict__ xl) {
  int lane = threadIdx.x & 63;
  const f32x4* w4 = (const f32x4*)Wrow + lane;
  const f32x4* x4 = (const f32x4*)xl + lane;
  f32x4 s = (f32x4)(0.f);
  #pragma unroll
  for (int g = 0; g < 8; ++g) s += w4[g * 64] * x4[g * 64];
  return s[0] + s[1] + s[2] + s[3];
}

// Fence-free grid barrier. Ordering: __syncthreads() drains vmcnt(0) in every
// wave (compiler-guaranteed before s_barrier), so the arrival atomicAdd (at
// IC) is issued only after all of this block's sc1 stores completed at IC.
// Pollers use a relaxed agent LOAD (concurrent, read-only). All NBLK blocks
// co-resident by construction (launch_bounds(256,4) -> 4 blk/CU * 256 CU).
__device__ __forceinline__ void grid_barrier(int* bar, int phase) {
  __syncthreads();
  if (threadIdx.x == 0) {
    atomicAdd(bar + phase, 1);
    while (__hip_atomic_load(bar + phase, __ATOMIC_RELAXED,
                             __HIP_MEMORY_SCOPE_AGENT) < NBLK)
      __builtin_amdgcn_s_sleep(8);
  }
  __syncthreads();
}

__global__ __launch_bounds__(256, 4)
void fused(const float* __restrict__ hidden, const int* __restrict__ inp,
           const float* __restrict__ emb, const float* __restrict__ stack,
           const float* __restrict__ Wc, const float* __restrict__ bc,
           const float* __restrict__ Ws, const float* __restrict__ bs,
           const float* __restrict__ Wih0, const float* __restrict__ bih0,
           const float* __restrict__ Whh0, const float* __restrict__ bhh0,
           const float* __restrict__ Wih1, const float* __restrict__ bih1,
           const float* __restrict__ Whh1, const float* __restrict__ bhh1,
           const float* __restrict__ Wd, const float* __restrict__ bd,
           float* __restrict__ ws, float* __restrict__ out) {
  __shared__ float xs[2048];   // phase-3/4 x staging (8 KB)
  int t = threadIdx.x;
  int lane = t & 63;
  int wgid = blockIdx.x * 4 + (t >> 6);
  int* bar = (int*)(ws + WS_BAR);

  // ---------------- Phase 1: all input-only matvecs (155 MB) ----------------
  for (int u = wgid; u < 18691; u += NWAVE) {
    if (u < 6144) {
      float d = wave_reduce(dot2048_part(Whh0 + (size_t)u * H, hidden));
      if (lane == 0) gstore(&ws[WS_GH0 + u], d + bhh0[u]);
    } else if (u < 12288) {
      int r = u - 6144;
      float d = wave_reduce(dot2048_part(Whh1 + (size_t)r * H, hidden + H));
      if (lane == 0) gstore(&ws[WS_GH1 + r], d + bhh1[r]);
    } else if (u < 18432) {
      int r = u - 12288;
      const float* erow = emb + (size_t)inp[0] * H;
      float d = wave_reduce(dot2048_part(Wih0 + (size_t)r * RIN, erow));
      if (lane == 0) gstore(&ws[WS_GI0 + r], d + bih0[r]);
    } else if (u < 18688) {
      int r = u - 18432;
      const float* wr = Ws + (size_t)r * (2 * H);
      float d = wave_reduce(dot2048_part(wr, hidden) +
                            dot2048_part(wr + H, hidden + H));
      if (lane == 0) gstore(&ws[WS_SDOT + r], d + bs[r]);
    } else {
      int r = u - 18688;
      const float* wr = Wc + (size_t)r * (2 * H);
      float d = wave_reduce(dot2048_part(wr, hidden) +
                            dot2048_part(wr + H, hidden + H));
      if (lane == 0) gstore(&ws[WS_CDOT + r], d + bc[r]);
    }
  }
  grid_barrier(bar, 0);

  // ------- Phase 2: stack update + GRU layer0 finish (wave-per-unit) --------
  {
    float c0 = gload(&ws[WS_CDOT + 0]);
    float c1 = gload(&ws[WS_CDOT + 1]);
    float c2 = gload(&ws[WS_CDOT + 2]);
    float m = fmaxf(c0, fmaxf(c1, c2));
    float e0 = expf(c0 - m), e1 = expf(c1 - m), e2 = expf(c2 - m);
    float inv = 1.f / (e0 + e1 + e2);
    float a_push = e0 * inv, a_pop = e1 * inv, a_noop = e2 * inv;
    int lane4 = lane * 4;

    if (wgid < 2048) {
      int j = wgid;
      f32x4 s0 = *(const f32x4*)(stack + lane4);
      f32x4 s1 = *(const f32x4*)(stack + SW + lane4);
      f32x4 sd, st;
      #pragma unroll
      for (int c = 0; c < 4; ++c) sd[c] = gload(&ws[WS_SDOT + lane4 + c]);
      #pragma unroll
      for (int c = 0; c < 4; ++c)
        st[c] = a_noop * s0[c] + a_push * tanhf(sd[c]) + a_pop * s1[c];
      float g[3];
      #pragma unroll
      for (int gate = 0; gate < 3; ++gate) {
        const f32x4* wrow =
            (const f32x4*)(Wih0 + (size_t)(gate * H + j) * RIN + H);
        f32x4 p = wrow[lane] * st;
        g[gate] = wave_reduce(p[0] + p[1] + p[2] + p[3]);
      }
      if (lane == 0) {
        float gr = gload(&ws[WS_GI0 + j]) + g[0] + gload(&ws[WS_GH0 + j]);
        float gz = gload(&ws[WS_GI0 + H + j]) + g[1] + gload(&ws[WS_GH0 + H + j]);
        float gn = gload(&ws[WS_GI0 + 2 * H + j]) + g[2];
        float r = sigmoidf(gr);
        float z = sigmoidf(gz);
        float n = tanhf(gn + r * gload(&ws[WS_GH0 + 2 * H + j]));
        gstore(&out[100 + j], (1.f - z) * n + z * hidden[j]);
      }
    } else if (wgid < 2048 + SD) {
      int r = wgid - 2048;
      f32x4 cur = *(const f32x4*)(stack + r * SW + lane4);
      f32x4 up, down;
      if (r == 0) {
        #pragma unroll
        for (int c = 0; c < 4; ++c)
          up[c] = tanhf(gload(&ws[WS_SDOT + lane4 + c]));
      } else {
        up = *(const f32x4*)(stack + (r - 1) * SW + lane4);
      }
      if (r == SD - 1) down = (f32x4)(0.f);
      else down = *(const f32x4*)(stack + (r + 1) * SW + lane4);
      f32x4 res = a_noop * cur + a_push * up + a_pop * down;
      *(f32x4*)(out + 4196 + r * SW + lane4) = res;  // final output, normal store
    }
  }
  grid_barrier(bar, 1);

  // ---------------- Phase 3: GRU layer1 (Wih1 @ h0, 50 MB) -----------------
  if (blockIdx.x < 512) {
    // stage h0 (cross-phase data) into LDS once per block via sc1 loads
    for (int i = t; i < 2048; i += 256) xs[i] = gload(&out[100 + i]);
    __syncthreads();
    int j = wgid;  // < 2048 by construction
    float dr = wave_reduce(row_dot_lds(Wih1 + (size_t)j * H, xs));
    float dz = wave_reduce(row_dot_lds(Wih1 + (size_t)(H + j) * H, xs));
    float dn = wave_reduce(row_dot_lds(Wih1 + (size_t)(2 * H + j) * H, xs));
    if (lane == 0) {
      float r = sigmoidf(dr + bih1[j] + gload(&ws[WS_GH1 + j]));
      float z = sigmoidf(dz + bih1[H + j] + gload(&ws[WS_GH1 + H + j]));
      float n = tanhf(dn + bih1[2 * H + j] + r * gload(&ws[WS_GH1 + 2 * H + j]));
      gstore(&out[100 + H + j], (1.f - z) * n + z * hidden[H + j]);
    }
  }
  grid_barrier(bar, 2);

  // ---------------- Phase 4: logits = Wd @ h1 + bd (0.8 MB) ----------------
  if (blockIdx.x < 25) {
    for (int i = t; i < 2048; i += 256) xs[i] = gload(&out[100 + H + i]);
    __syncthreads();
    if (wgid < 100) {
      float d = wave_reduce(row_dot_lds(Wd + (size_t)wgid * H, xs));
      if (lane == 0) out[wgid] = d + bd[wgid];  // final output, normal store
    }
  }
}

extern "C" void kernel_launch(void* const* d_in, const int* in_sizes, int n_in,
                              void* d_out, int out_size, void* d_ws, size_t ws_size,
                              hipStream_t stream) {
  const int*   inp    = (const int*)d_in[0];
  const float* hidden = (const float*)d_in[1];
  const float* stack  = (const float*)d_in[2];
  const float* emb    = (const float*)d_in[3];
  const float* Wc     = (const float*)d_in[4];
  const float* bc     = (const float*)d_in[5];
  const float* Ws     = (const float*)d_in[6];
  const float* bs     = (const float*)d_in[7];
  const float* Wih0   = (const float*)d_in[8];
  const float* Whh0   = (const float*)d_in[9];
  const float* bih0   = (const float*)d_in[10];
  const float* bhh0   = (const float*)d_in[11];
  const float* Wih1   = (const float*)d_in[12];
  const float* Whh1   = (const float*)d_in[13];
  const float* bih1   = (const float*)d_in[14];
  const float* bhh1   = (const float*)d_in[15];
  const float* Wd     = (const float*)d_in[16];
  const float* bd     = (const float*)d_in[17];
  float* ws  = (float*)d_ws;
  float* out = (float*)d_out;

  // zero the 3 barrier counters (d_ws is poisoned 0xAA once, never re-poisoned)
  hipMemsetAsync((char*)d_ws + WS_BAR * sizeof(float), 0, 3 * sizeof(int), stream);
  fused<<<NBLK, 256, 0, stream>>>(hidden, inp, emb, stack, Wc, bc, Ws, bs,
                                  Wih0, bih0, Whh0, bhh0, Wih1, bih1,
                                  Whh1, bhh1, Wd, bd, ws, out);
}

// Round 10
// 44.747 us; speedup vs baseline: 11.5189x; 3.9931x over previous
//
#include <hip/hip_runtime.h>
#include <hip/hip_bf16.h>

#define H 2048
#define RIN 2304
#define SW 256
#define SD 200

// ws layout (floats):
#define WS_CDOT 0
#define WS_SDOT 4
#define WS_GH0  260
#define WS_GH1  6404
#define WS_GI0  12548

// out layout (floats): [0..100) logits, [100..2148) h0, [2148..4196) h1,
// [4196..55396) new_stack (200x256)
//
// R10 note: this is the R2 kernel verbatim — best measured (44.5 us).
// Fusion attempts (R7-R9) are structurally dominated: any software grid
// barrier costs >= ~46 us (1024 same-line RMW arrivals @ ~45ns at the IC
// coherence point; fences cost ~170 us each via L2 writeback/invalidate),
// while a graph-replayed kernel-launch gap is ~2 us. Keep 4 kernels.

typedef __attribute__((ext_vector_type(4))) float f32x4;

__device__ __forceinline__ float wave_reduce(float acc) {
  #pragma unroll
  for (int off = 32; off > 0; off >>= 1) acc += __shfl_down(acc, off);
  return acc;  // valid in lane 0
}

// Per-lane partial dot over 2048 elements, fully unrolled.
__device__ __forceinline__ float dot2048_part(const float* __restrict__ w,
                                              const float* __restrict__ x) {
  int lane = threadIdx.x & 63;
  const float4* w4 = (const float4*)w + lane;
  const float4* x4 = (const float4*)x + lane;
  float4 a0 = w4[0],   a1 = w4[64],  a2 = w4[128], a3 = w4[192];
  float4 a4 = w4[256], a5 = w4[320], a6 = w4[384], a7 = w4[448];
  float4 b0 = x4[0],   b1 = x4[64],  b2 = x4[128], b3 = x4[192];
  float4 b4 = x4[256], b5 = x4[320], b6 = x4[384], b7 = x4[448];
  float acc = a0.x * b0.x + a0.y * b0.y + a0.z * b0.z + a0.w * b0.w;
  acc += a1.x * b1.x + a1.y * b1.y + a1.z * b1.z + a1.w * b1.w;
  acc += a2.x * b2.x + a2.y * b2.y + a2.z * b2.z + a2.w * b2.w;
  acc += a3.x * b3.x + a3.y * b3.y + a3.z * b3.z + a3.w * b3.w;
  acc += a4.x * b4.x + a4.y * b4.y + a4.z * b4.z + a4.w * b4.w;
  acc += a5.x * b5.x + a5.y * b5.y + a5.z * b5.z + a5.w * b5.w;
  acc += a6.x * b6.x + a6.y * b6.y + a6.z * b6.z + a6.w * b6.w;
  acc += a7.x * b7.x + a7.y * b7.y + a7.z * b7.z + a7.w * b7.w;
  return acc;
}

__device__ __forceinline__ float sigmoidf(float x) {
  return 1.f / (1.f + expf(-x));
}

// K1: all input-only matvecs. wave-per-row.
__global__ __launch_bounds__(256)
void k1_matvecs(const float* __restrict__ hidden, const int* __restrict__ inp,
                const float* __restrict__ emb,
                const float* __restrict__ Wc, const float* __restrict__ bc,
                const float* __restrict__ Ws, const float* __restrict__ bs,
                const float* __restrict__ Wih0, const float* __restrict__ bih0,
                const float* __restrict__ Whh0, const float* __restrict__ bhh0,
                const float* __restrict__ Whh1, const float* __restrict__ bhh1,
                float* __restrict__ ws) {
  int w = blockIdx.x * 4 + (threadIdx.x >> 6);
  int lane = threadIdx.x & 63;
  if (w < 6144) {
    float d = wave_reduce(dot2048_part(Whh0 + (size_t)w * H, hidden));
    if (lane == 0) ws[WS_GH0 + w] = d + bhh0[w];
  } else if (w < 12288) {
    int r = w - 6144;
    float d = wave_reduce(dot2048_part(Whh1 + (size_t)r * H, hidden + H));
    if (lane == 0) ws[WS_GH1 + r] = d + bhh1[r];
  } else if (w < 18432) {
    int r = w - 12288;
    const float* erow = emb + (size_t)inp[0] * H;
    float d = wave_reduce(dot2048_part(Wih0 + (size_t)r * RIN, erow));
    if (lane == 0) ws[WS_GI0 + r] = d + bih0[r];
  } else if (w < 18435) {
    int r = w - 18432;
    const float* wr = Wc + (size_t)r * (2 * H);
    float d = wave_reduce(dot2048_part(wr, hidden) +
                          dot2048_part(wr + H, hidden + H));
    if (lane == 0) ws[WS_CDOT + r] = d + bc[r];
  } else if (w < 18691) {
    int r = w - 18435;
    const float* wr = Ws + (size_t)r * (2 * H);
    float d = wave_reduce(dot2048_part(wr, hidden) +
                          dot2048_part(wr + H, hidden + H));
    if (lane == 0) ws[WS_SDOT + r] = d + bs[r];
  }
}

// K2: blocks [0,2048): GRU layer0 finish (one j per block; 3 waves do the
//     K=256 stack-column dots of Wih0); blocks [2048,2248): new_stack rows.
__global__ __launch_bounds__(256)
void k2_stack_gru0(const float* __restrict__ stack,
                   const float* __restrict__ hidden,
                   const float* __restrict__ Wih0,
                   const float* __restrict__ ws,
                   float* out) {
  int t = threadIdx.x;
  float c0 = ws[WS_CDOT + 0], c1 = ws[WS_CDOT + 1], c2 = ws[WS_CDOT + 2];
  float m = fmaxf(c0, fmaxf(c1, c2));
  float e0 = expf(c0 - m), e1 = expf(c1 - m), e2 = expf(c2 - m);
  float inv = 1.f / (e0 + e1 + e2);
  float a_push = e0 * inv, a_pop = e1 * inv, a_noop = e2 * inv;

  int b = blockIdx.x;
  if (b >= 2048) {
    int r = b - 2048;
    float up = (r == 0) ? tanhf(ws[WS_SDOT + t]) : stack[(r - 1) * SW + t];
    float down = (r == SD - 1) ? 0.f : stack[(r + 1) * SW + t];
    out[4196 + r * SW + t] = a_noop * stack[r * SW + t] + a_push * up + a_pop * down;
    return;
  }
  __shared__ float st[SW];
  __shared__ float gred[3];
  st[t] = a_noop * stack[t] + a_push * tanhf(ws[WS_SDOT + t]) + a_pop * stack[SW + t];
  __syncthreads();
  int wv = t >> 6, lane = t & 63;
  int j = b;
  if (wv < 3) {
    const f32x4* w4 = (const f32x4*)(Wih0 + (size_t)(wv * H + j) * RIN + H);
    const f32x4* s4 = (const f32x4*)st;
    f32x4 a = w4[lane];
    f32x4 xv = s4[lane];
    f32x4 p = a * xv;
    float acc = wave_reduce(p[0] + p[1] + p[2] + p[3]);
    if (lane == 0) gred[wv] = acc;
  }
  __syncthreads();
  if (t == 0) {
    float gr = ws[WS_GI0 + j] + gred[0] + ws[WS_GH0 + j];
    float gz = ws[WS_GI0 + H + j] + gred[1] + ws[WS_GH0 + H + j];
    float r = sigmoidf(gr);
    float z = sigmoidf(gz);
    float n = tanhf(ws[WS_GI0 + 2 * H + j] + gred[2] + r * ws[WS_GH0 + 2 * H + j]);
    out[100 + j] = (1.f - z) * n + z * hidden[j];
  }
}

// K3: GRU layer1, fused matvec + combine. One j per block, 3 waves (192 thr).
__global__ __launch_bounds__(192)
void k3_gru1(const float* __restrict__ hidden,
             const float* __restrict__ Wih1, const float* __restrict__ bih1,
             const float* __restrict__ ws,
             float* out) {
  int j = blockIdx.x;
  int t = threadIdx.x, wv = t >> 6, lane = t & 63;
  const float* h0 = out + 100;  // written by k2
  __shared__ float gred[3];
  int row = wv * H + j;
  float d = wave_reduce(dot2048_part(Wih1 + (size_t)row * H, h0));
  if (lane == 0) gred[wv] = d + bih1[row];
  __syncthreads();
  if (t == 0) {
    float r = sigmoidf(gred[0] + ws[WS_GH1 + j]);
    float z = sigmoidf(gred[1] + ws[WS_GH1 + H + j]);
    float n = tanhf(gred[2] + r * ws[WS_GH1 + 2 * H + j]);
    out[100 + H + j] = (1.f - z) * n + z * hidden[H + j];
  }
}

// K4: logits = Wd @ h1 + bd. wave-per-row, 100 rows.
__global__ __launch_bounds__(256)
void k4_logits(const float* __restrict__ Wd, const float* __restrict__ bd,
               float* out) {
  int w = blockIdx.x * 4 + (threadIdx.x >> 6);
  int lane = threadIdx.x & 63;
  if (w >= 100) return;
  const float* h1 = out + 100 + H;  // written by k3
  float d = wave_reduce(dot2048_part(Wd + (size_t)w * H, h1));
  if (lane == 0) out[w] = d + bd[w];
}

extern "C" void kernel_launch(void* const* d_in, const int* in_sizes, int n_in,
                              void* d_out, int out_size, void* d_ws, size_t ws_size,
                              hipStream_t stream) {
  const int*   inp    = (const int*)d_in[0];
  const float* hidden = (const float*)d_in[1];
  const float* stack  = (const float*)d_in[2];
  const float* emb    = (const float*)d_in[3];
  const float* Wc     = (const float*)d_in[4];
  const float* bc     = (const float*)d_in[5];
  const float* Ws     = (const float*)d_in[6];
  const float* bs     = (const float*)d_in[7];
  const float* Wih0   = (const float*)d_in[8];
  const float* Whh0   = (const float*)d_in[9];
  const float* bih0   = (const float*)d_in[10];
  const float* bhh0   = (const float*)d_in[11];
  const float* Wih1   = (const float*)d_in[12];
  const float* Whh1   = (const float*)d_in[13];
  const float* bih1   = (const float*)d_in[14];
  const float* bhh1   = (const float*)d_in[15];
  const float* Wd     = (const float*)d_in[16];
  const float* bd     = (const float*)d_in[17];
  float* ws  = (float*)d_ws;
  float* out = (float*)d_out;

  k1_matvecs<<<4673, 256, 0, stream>>>(hidden, inp, emb, Wc, bc, Ws, bs,
                                       Wih0, bih0, Whh0, bhh0, Whh1, bhh1, ws);
  k2_stack_gru0<<<2248, 256, 0, stream>>>(stack, hidden, Wih0, ws, out);
  k3_gru1<<<2048, 192, 0, stream>>>(hidden, Wih1, bih1, ws, out);
  k4_logits<<<25, 256, 0, stream>>>(Wd, bd, out);
}